// Round 3
// baseline (1049.385 us; speedup 1.0000x reference)
//
#include <hip/hip_runtime.h>

// ConvLSTM cell, MI355X. Single implicit-GEMM over concat(x,h) channels with
// bf16 MFMA (32x32x16), fused in-register LSTM epilogue.
// R3: R2 pipeline with the B-frag read-base bug fixed (no +1 padding on read).

typedef __bf16 bf16x8 __attribute__((ext_vector_type(8)));
typedef float f32x16 __attribute__((ext_vector_type(16)));

#define XH_ELTS   33554432u   // 256 b * 16 icblk * 256 s * 32 c
#define OUT_HALF  16777216u   // B*CH*S

// ---------------------------------------------------------------------------
// P1a: x,h (NCHW fp32) -> xh bf16, layout [b][icblk(16)][s(256)][c(32)]
__global__ __launch_bounds__(256) void xh_transform(
    const float* __restrict__ x, const float* __restrict__ hh,
    __bf16* __restrict__ xh)
{
    int blk = blockIdx.x;              // b*16 + ib
    int b = blk >> 4, ib = blk & 15;
    const float* src = (ib < 8) ? (x  + ((size_t)(b*256 + ib*32)) * 256)
                                : (hh + ((size_t)(b*256 + (ib-8)*32)) * 256);
    int t = threadIdx.x;               // t == spatial s
    uint32_t w[16];
#pragma unroll
    for (int i = 0; i < 16; ++i) {
        __bf16 lo = (__bf16)src[(size_t)(2*i  )*256 + t];
        __bf16 hi = (__bf16)src[(size_t)(2*i+1)*256 + t];
        w[i] = (uint32_t)__builtin_bit_cast(unsigned short, lo)
             | ((uint32_t)__builtin_bit_cast(unsigned short, hi) << 16);
    }
    uint4* dst = (uint4*)(xh + (size_t)blk*8192 + (size_t)t*32);
#pragma unroll
    for (int i = 0; i < 4; ++i)
        dst[i] = uint4{w[4*i], w[4*i+1], w[4*i+2], w[4*i+3]};
}

// ---------------------------------------------------------------------------
// P1b: Wx,Wh (OIHW fp32) -> Wt bf16 in A-fragment order.
__global__ __launch_bounds__(256) void w_transform(
    const float* __restrict__ Wx, const float* __restrict__ Wh,
    __bf16* __restrict__ Wt)
{
    int idx  = blockIdx.x * 256 + threadIdx.x;   // 589824 total
    int lane = idx & 63;
    int chunk = idx >> 6;                        // 9216 chunks
    int half  = chunk & 1;
    int icblk = (chunk >> 1) & 15;
    int fg    = (chunk >> 5) & 3;
    int cb    = (chunk >> 7) & 7;
    int pos   = chunk >> 10;                     // ky*3+kx
    int row = lane & 31, hl = lane >> 5;
    int gate = row & 3, ch8 = row >> 2;
    int oc  = gate*256 + cb*32 + fg*8 + ch8;
    int ic0 = icblk*32 + half*16 + hl*8;
    bf16x8 v;
#pragma unroll
    for (int j = 0; j < 8; ++j) {
        int ic = ic0 + j;
        float w = (ic < 256) ? Wx[((size_t)oc*256 + ic      )*9 + pos]
                             : Wh[((size_t)oc*256 + (ic-256))*9 + pos];
        v[j] = (__bf16)w;
    }
    *(bf16x8*)(Wt + (size_t)chunk*512 + (size_t)lane*8) = v;
}

// ---------------------------------------------------------------------------
// Main kernel. Block = (b, cb); 4 waves 2x2; tile 128 oc' x 256 spatial.
// 18 phases per ic-block (9 taps x 2 k-halves), software-pipelined:
//   A-frag (global, Wt) prefetch distance 2, carried across ib boundary;
//   B-frag (LDS) prefetch distance 1, restarted after each barrier;
//   setprio around MFMA cluster.
__global__ __launch_bounds__(256, 2) void convlstm_main(
    const __bf16* __restrict__ xh, const __bf16* __restrict__ Wt,
    const float* __restrict__ bh,  const float* __restrict__ cin,
    const float* __restrict__ Wci, const float* __restrict__ Wcf,
    const float* __restrict__ Wco, float* __restrict__ out)
{
    int bid = blockIdx.x;
    int cb  = bid & 7;
    int b   = bid >> 3;
    int tid = threadIdx.x;
    int lane = tid & 63;
    int wid  = tid >> 6;
    int l31  = lane & 31;
    int hl   = lane >> 5;
    int wm = wid & 1, wn = wid >> 1;

    __shared__ __align__(16) unsigned short lds[2][18*18*32];

    // zero both buffers (borders must stay 0 for SAME padding)
    {
        uint32_t* p = (uint32_t*)&lds[0][0];
        for (int i = tid; i < (2*18*18*32)/2; i += 256) p[i] = 0u;
    }

    // accumulators init with bias bh[oc]
    f32x16 acc[4][2];
#pragma unroll
    for (int f = 0; f < 2; ++f) {
        int fg = wn*2 + f;
        f32x16 v;
#pragma unroll
        for (int r = 0; r < 16; ++r) {
            int gate = r & 3, q = r >> 2;
            v[r] = bh[gate*256 + cb*32 + fg*8 + 2*q + hl];
        }
        acc[0][f] = v; acc[1][f] = v; acc[2][f] = v; acc[3][f] = v;
    }
    __syncthreads();

    // staging: thread t <-> spatial s; padded pos p_pad = (y+1)*18+(x+1)
    const int s = tid;
    const int p_pad = ((s >> 4) + 1)*18 + (s & 15) + 1;
    const uint32_t wby  = (uint32_t)p_pad * 64u;
    const uint32_t wswz = ((uint32_t)(p_pad & 7)) << 4;
    const __bf16* xb = xh + (size_t)b * (16*8192);

    // stage ic-block 0 into buffer 0
    {
        const uint4* g = (const uint4*)(xb + (size_t)s*32);
        uint4 a0=g[0], a1=g[1], a2=g[2], a3=g[3];
        char* p0 = (char*)&lds[0][0];
        *(uint4*)(p0 + ((wby+ 0)^wswz)) = a0;
        *(uint4*)(p0 + ((wby+16)^wswz)) = a1;
        *(uint4*)(p0 + ((wby+32)^wswz)) = a2;
        *(uint4*)(p0 + ((wby+48)^wswz)) = a3;
    }
    __syncthreads();

    // per-wave B-frag read bases: output coord (no +1 — tap offset dky,dkx
    // added directly indexes the padded plane; R2's +1 bug caused OOB/NaN)
    int pbase[4];
#pragma unroll
    for (int mf = 0; mf < 4; ++mf) {
        int m = wm*128 + mf*32 + l31;
        pbase[mf] = (m >> 4)*18 + (m & 15);
    }

    const __bf16* wlane = Wt + (size_t)lane*8;
    auto achunk = [&](int ib, int ph, int f) -> size_t {
        int pos = ph >> 1, half = ph & 1, fg = wn*2 + f;
        return ((size_t)((pos*8 + cb)*4 + fg))*32 + (size_t)(ib*2 + half);
    };

    const char* rb = (const char*)&lds[0][0];
    auto bread = [&](int mf, int ph) -> bf16x8 {
        int pos = ph >> 1, half = ph & 1;
        int p = pbase[mf] + (pos/3)*18 + (pos%3);
        uint32_t byte = (((uint32_t)p)*64u + (uint32_t)(half*32 + hl*16))
                        ^ (((uint32_t)(p & 7)) << 4);
        return *(const bf16x8*)(rb + byte);
    };

    // A-prefetch prologue: phases 0,1 of ib 0
    bf16x8 A[3][2];
#pragma unroll
    for (int f = 0; f < 2; ++f) {
        A[0][f] = *(const bf16x8*)(wlane + achunk(0, 0, f)*512);
        A[1][f] = *(const bf16x8*)(wlane + achunk(0, 1, f)*512);
    }

    for (int ib = 0; ib < 16; ++ib) {
        const int cur = ib & 1;
        const int ibn = (ib < 15) ? ib + 1 : 15;
        rb = (const char*)&lds[cur][0];

        // issue next-block staging loads first (oldest in vmcnt queue;
        // consumed only at ib end -> latency hidden under 18 MFMA phases)
        uint4 s0, s1, s2, s3;
        {
            const uint4* g = (const uint4*)(xb + (size_t)ibn*8192 + (size_t)s*32);
            s0 = g[0]; s1 = g[1]; s2 = g[2]; s3 = g[3];
        }

        // B pipeline restart: phase 0 reads
        bf16x8 Bb[2][4];
#pragma unroll
        for (int mf = 0; mf < 4; ++mf) Bb[0][mf] = bread(mf, 0);

#pragma unroll
        for (int ph = 0; ph < 18; ++ph) {
            // A prefetch distance 2 (crosses ib boundary at ph 16/17)
            {
                const int aib_is_cur = (ph < 16);
                int aib = aib_is_cur ? ib : ibn;
                int aph = aib_is_cur ? ph + 2 : ph - 16;
#pragma unroll
                for (int f = 0; f < 2; ++f)
                    A[(ph+2)%3][f] =
                        *(const bf16x8*)(wlane + achunk(aib, aph, f)*512);
            }
            // B prefetch distance 1
            if (ph < 17) {
#pragma unroll
                for (int mf = 0; mf < 4; ++mf)
                    Bb[(ph+1)&1][mf] = bread(mf, ph+1);
            }
            __builtin_amdgcn_s_setprio(1);
#pragma unroll
            for (int mf = 0; mf < 4; ++mf)
#pragma unroll
                for (int f = 0; f < 2; ++f)
                    acc[mf][f] = __builtin_amdgcn_mfma_f32_32x32x16_bf16(
                        A[ph%3][f], Bb[ph&1][mf], acc[mf][f], 0, 0, 0);
            __builtin_amdgcn_s_setprio(0);
        }

        // stage write into the other buffer (harmless on last iter)
        {
            char* pw = (char*)&lds[cur ^ 1][0];
            *(uint4*)(pw + ((wby+ 0)^wswz)) = s0;
            *(uint4*)(pw + ((wby+16)^wswz)) = s1;
            *(uint4*)(pw + ((wby+32)^wswz)) = s2;
            *(uint4*)(pw + ((wby+48)^wswz)) = s3;
        }
        __syncthreads();
    }

    // fused LSTM epilogue, fully in-register.
    // D layout (32x32): col = lane&31 (m), r = 4*q + gate,
    // ch = cb*32 + fg*8 + 2*q + hl.
    float* outh = out;
    float* outc = out + (size_t)OUT_HALF;
    const size_t bOff = (size_t)b * (256*256);
#pragma unroll
    for (int mf = 0; mf < 4; ++mf) {
        int m = wm*128 + mf*32 + l31;
#pragma unroll
        for (int f = 0; f < 2; ++f) {
            int fg = wn*2 + f;
#pragma unroll
            for (int q = 0; q < 4; ++q) {
                int ch = cb*32 + fg*8 + 2*q + hl;
                size_t pidx = (size_t)ch*256 + (size_t)m;
                size_t idx  = bOff + pidx;
                float cv = cin[idx];
                float pi = acc[mf][f][4*q+0];
                float pf = acc[mf][f][4*q+1];
                float pc = acc[mf][f][4*q+2];
                float po = acc[mf][f][4*q+3];
                float it = 1.f/(1.f + __expf(-(pi + Wci[pidx]*cv)));
                float ft = 1.f/(1.f + __expf(-(pf + Wcf[pidx]*cv)));
                float tc = 1.f - 2.f/(1.f + __expf(2.f*pc));
                float ct = ft*cv + it*tc;
                float ot = 1.f/(1.f + __expf(-(po + Wco[pidx]*ct)));
                float th = 1.f - 2.f/(1.f + __expf(2.f*ct));
                outh[idx] = ot*th;
                outc[idx] = ct;
            }
        }
    }
}

// ---------------------------------------------------------------------------
extern "C" void kernel_launch(void* const* d_in, const int* in_sizes, int n_in,
                              void* d_out, int out_size, void* d_ws, size_t ws_size,
                              hipStream_t stream)
{
    const float* x   = (const float*)d_in[0];
    const float* h   = (const float*)d_in[1];
    const float* c   = (const float*)d_in[2];
    const float* Wx  = (const float*)d_in[3];
    const float* Wh  = (const float*)d_in[4];
    const float* bh  = (const float*)d_in[5];
    const float* Wci = (const float*)d_in[6];
    const float* Wcf = (const float*)d_in[7];
    const float* Wco = (const float*)d_in[8];
    float* out = (float*)d_out;

    __bf16* xh = (__bf16*)d_ws;                 // 67,108,864 B
    __bf16* Wt = xh + (size_t)XH_ELTS;          // + 9,437,184 B

    hipLaunchKernelGGL(xh_transform, dim3(4096), dim3(256), 0, stream, x, h, xh);
    hipLaunchKernelGGL(w_transform,  dim3(2304), dim3(256), 0, stream, Wx, Wh, Wt);
    hipLaunchKernelGGL(convlstm_main, dim3(2048), dim3(256), 0, stream,
                       xh, Wt, bh, c, Wci, Wcf, Wco, out);
}

// Round 4
// 651.092 us; speedup vs baseline: 1.6117x; 1.6117x over previous
//
#include <hip/hip_runtime.h>

// ConvLSTM cell, MI355X. Implicit-GEMM over concat(x,h) channels, bf16 MFMA
// 32x32x16, fused in-register LSTM epilogue.
// R4: 64-AGPR wave tile (64m x 64oc), pre-padded pre-swizzled planes in ws,
// global_load_lds staging (linear dest), dist-1 A prefetch, setprio.

typedef __bf16 bf16x8 __attribute__((ext_vector_type(8)));
typedef float f32x16 __attribute__((ext_vector_type(16)));

#define PLANE_B  20736u                 // 324 positions * 64 B (18x18x32 bf16)
#define XH_BYTES (4096u * PLANE_B)      // 256 b * 16 icblk planes = 84,934,656
#define OUT_HALF 16777216u              // B*CH*S

__device__ inline void gload_lds16(const void* g, void* l) {
    __builtin_amdgcn_global_load_lds(
        (const __attribute__((address_space(1))) void*)g,
        (__attribute__((address_space(3))) void*)l, 16, 0, 0);
}

// ---------------------------------------------------------------------------
// P1a: x,h (NCHW fp32) -> padded swizzled bf16 planes.
// Plane (b, ibk): 18x18 positions x 32 ch x 2 B, zero border, byte layout
// addr = (p*64 + ofs) ^ ((p&7)<<4)  (bijective; same formula on read).
__global__ __launch_bounds__(256) void xh_transform(
    const float* __restrict__ x, const float* __restrict__ hh,
    unsigned char* __restrict__ xh)
{
    int blk = blockIdx.x;              // b*16 + ibk
    int b = blk >> 4, ibk = blk & 15;
    const float* src = (ibk < 8) ? (x  + ((size_t)(b*256 + ibk*32)) * 256)
                                 : (hh + ((size_t)(b*256 + (ibk-8)*32)) * 256);
    int t = threadIdx.x;               // t == spatial s
    uint32_t w[16];
#pragma unroll
    for (int i = 0; i < 16; ++i) {
        __bf16 lo = (__bf16)src[(size_t)(2*i  )*256 + t];
        __bf16 hi = (__bf16)src[(size_t)(2*i+1)*256 + t];
        w[i] = (uint32_t)__builtin_bit_cast(unsigned short, lo)
             | ((uint32_t)__builtin_bit_cast(unsigned short, hi) << 16);
    }
    unsigned char* plane = xh + (size_t)blk * PLANE_B;
    int p = ((t >> 4) + 1)*18 + (t & 15) + 1;      // interior position
    uint32_t key  = (uint32_t)(p & 7) << 4;
    uint32_t base = (uint32_t)p * 64u;
#pragma unroll
    for (int k = 0; k < 4; ++k)
        *(uint4*)(plane + ((base + 16u*k) ^ key)) =
            uint4{w[4*k], w[4*k+1], w[4*k+2], w[4*k+3]};
    // zero the 68 border positions (rows 0,17; cols 0,17)
    if (t < 68) {
        int pb;
        if      (t < 18) pb = t;                   // row 0
        else if (t < 36) pb = 17*18 + (t - 18);    // row 17
        else if (t < 52) pb = (t - 35)*18;         // rows 1..16, col 0
        else             pb = (t - 51)*18 + 17;    // rows 1..16, col 17
        uint32_t kb = (uint32_t)(pb & 7) << 4;
        uint32_t bb = (uint32_t)pb * 64u;
        uint4 z{0u,0u,0u,0u};
#pragma unroll
        for (int k = 0; k < 4; ++k)
            *(uint4*)(plane + ((bb + 16u*k) ^ kb)) = z;
    }
}

// ---------------------------------------------------------------------------
// P1b: Wx,Wh (OIHW fp32) -> Wt bf16 in A-fragment order (unchanged from R1).
__global__ __launch_bounds__(256) void w_transform(
    const float* __restrict__ Wx, const float* __restrict__ Wh,
    __bf16* __restrict__ Wt)
{
    int idx  = blockIdx.x * 256 + threadIdx.x;   // 589824 total
    int lane = idx & 63;
    int chunk = idx >> 6;                        // 9216 chunks
    int half  = chunk & 1;
    int icblk = (chunk >> 1) & 15;
    int fg    = (chunk >> 5) & 3;
    int cb    = (chunk >> 7) & 7;
    int pos   = chunk >> 10;                     // ky*3+kx
    int row = lane & 31, hl = lane >> 5;
    int gate = row & 3, ch8 = row >> 2;
    int oc  = gate*256 + cb*32 + fg*8 + ch8;
    int ic0 = icblk*32 + half*16 + hl*8;
    bf16x8 v;
#pragma unroll
    for (int j = 0; j < 8; ++j) {
        int ic = ic0 + j;
        float w = (ic < 256) ? Wx[((size_t)oc*256 + ic      )*9 + pos]
                             : Wh[((size_t)oc*256 + (ic-256))*9 + pos];
        v[j] = (__bf16)w;
    }
    *(bf16x8*)(Wt + (size_t)chunk*512 + (size_t)lane*8) = v;
}

// ---------------------------------------------------------------------------
// Main. Block = (b, nh, cb): 256m x 64oc' (2 fg groups). 4 waves, each
// 64m x 64oc: acc[2][2] f32x16 = 64 AGPR. Staging via global_load_lds
// (6 x 1KB per wave) into double-buffered 24576-B LDS planes.
__global__ __launch_bounds__(256, 2) void convlstm_main(
    const unsigned char* __restrict__ xh, const __bf16* __restrict__ Wt,
    const float* __restrict__ bh,  const float* __restrict__ cin,
    const float* __restrict__ Wci, const float* __restrict__ Wcf,
    const float* __restrict__ Wco, float* __restrict__ out)
{
    int bid = blockIdx.x;               // b*16 + nh*8 + cb
    int cb  = bid & 7;
    int nh  = (bid >> 3) & 1;
    int b   = bid >> 4;
    int tid = threadIdx.x;
    int lane = tid & 63, wv = tid >> 6;
    int l31 = lane & 31, hl = lane >> 5;

    __shared__ __align__(16) unsigned char lds[2][24576];

    // accumulators init with bias bh[oc]
    f32x16 acc[2][2];
#pragma unroll
    for (int f = 0; f < 2; ++f) {
        int fg = nh*2 + f;
        f32x16 v;
#pragma unroll
        for (int r = 0; r < 16; ++r) {
            int gate = r & 3, q = r >> 2;
            v[r] = bh[gate*256 + cb*32 + fg*8 + 2*q + hl];
        }
        acc[0][f] = v; acc[1][f] = v;
    }

    const unsigned char* planes = xh + (size_t)b * (16u * PLANE_B);

    // stage plane 0 into buffer 0 (linear DMA; plane is pre-padded+swizzled)
#pragma unroll
    for (int k = 0; k < 6; ++k)
        gload_lds16(planes + (size_t)(wv*6 + k)*1024u + (size_t)lane*16u,
                    &lds[0][(wv*6 + k)*1024 + lane*16]);

    // per-wave B-frag position bases (m = wv*64 + mf*32 + l31)
    int m0 = wv*64 + l31,       m1 = wv*64 + 32 + l31;
    int pbase0 = (m0 >> 4)*18 + (m0 & 15);
    int pbase1 = (m1 >> 4)*18 + (m1 & 15);

    const __bf16* wlane = Wt + (size_t)lane * 8;
    auto achunk = [&](int ibk, int ph, int f) -> size_t {
        int pos = ph >> 1, half = ph & 1, fg = nh*2 + f;
        return ((size_t)((pos*8 + cb)*4 + fg))*32 + (size_t)(ibk*2 + half);
    };

    __syncthreads();   // drains stage DMA (vmcnt) + joins waves

    // A prologue: phase 0 of icblk 0
    bf16x8 A[2][2];
    A[0][0] = *(const bf16x8*)(wlane + achunk(0, 0, 0)*512);
    A[0][1] = *(const bf16x8*)(wlane + achunk(0, 0, 1)*512);

    for (int ibk = 0; ibk < 16; ++ibk) {
        const int cur = ibk & 1;
        // issue next-plane DMA into the buffer freed by last iteration
        if (ibk < 15) {
            const unsigned char* np = planes + (size_t)(ibk+1) * PLANE_B;
#pragma unroll
            for (int k = 0; k < 6; ++k)
                gload_lds16(np + (size_t)(wv*6 + k)*1024u + (size_t)lane*16u,
                            &lds[cur ^ 1][(wv*6 + k)*1024 + lane*16]);
        }
        const unsigned char* rb = lds[cur];
#pragma unroll
        for (int ph = 0; ph < 18; ++ph) {
            // A prefetch distance 1 (wraps into next icblk at ph 17)
            {
                int nib = (ph < 17) ? ibk : ((ibk < 15) ? ibk + 1 : ibk);
                int nph = (ph < 17) ? ph + 1 : 0;
                A[(ph+1)&1][0] = *(const bf16x8*)(wlane + achunk(nib, nph, 0)*512);
                A[(ph+1)&1][1] = *(const bf16x8*)(wlane + achunk(nib, nph, 1)*512);
            }
            const int pos = ph >> 1, half = ph & 1;
            const int dp = (pos/3)*18 + (pos%3);
            const uint32_t kofs = (uint32_t)(half*32 + hl*16);
            bf16x8 B0, B1;
            {
                int p = pbase0 + dp;
                uint32_t byte = ((uint32_t)p*64u + kofs) ^ ((uint32_t)(p&7) << 4);
                B0 = *(const bf16x8*)(rb + byte);
            }
            {
                int p = pbase1 + dp;
                uint32_t byte = ((uint32_t)p*64u + kofs) ^ ((uint32_t)(p&7) << 4);
                B1 = *(const bf16x8*)(rb + byte);
            }
            __builtin_amdgcn_s_setprio(1);
            acc[0][0] = __builtin_amdgcn_mfma_f32_32x32x16_bf16(A[ph&1][0], B0, acc[0][0], 0, 0, 0);
            acc[0][1] = __builtin_amdgcn_mfma_f32_32x32x16_bf16(A[ph&1][1], B0, acc[0][1], 0, 0, 0);
            acc[1][0] = __builtin_amdgcn_mfma_f32_32x32x16_bf16(A[ph&1][0], B1, acc[1][0], 0, 0, 0);
            acc[1][1] = __builtin_amdgcn_mfma_f32_32x32x16_bf16(A[ph&1][1], B1, acc[1][1], 0, 0, 0);
            __builtin_amdgcn_s_setprio(0);
        }
        __syncthreads();   // drains DMA for next buffer; separates buffers
    }

    // fused LSTM epilogue. D layout: col = l31 (m), D_row = (r&3)+8*(r>>2)+4*hl
    // -> gate = r&3, ch = cb*32 + fg*8 + 2*(r>>2) + hl.
    float* outh = out;
    float* outc = out + (size_t)OUT_HALF;
    const size_t bOff = (size_t)b * (256*256);
#pragma unroll
    for (int mf = 0; mf < 2; ++mf) {
        int m = wv*64 + mf*32 + l31;
#pragma unroll
        for (int f = 0; f < 2; ++f) {
            int fg = nh*2 + f;
#pragma unroll
            for (int q = 0; q < 4; ++q) {
                int ch = cb*32 + fg*8 + 2*q + hl;
                size_t pidx = (size_t)ch*256 + (size_t)m;
                size_t idx  = bOff + pidx;
                float cv = cin[idx];
                float pi = acc[mf][f][4*q+0];
                float pf = acc[mf][f][4*q+1];
                float pc = acc[mf][f][4*q+2];
                float po = acc[mf][f][4*q+3];
                float it = 1.f/(1.f + __expf(-(pi + Wci[pidx]*cv)));
                float ft = 1.f/(1.f + __expf(-(pf + Wcf[pidx]*cv)));
                float tc = 1.f - 2.f/(1.f + __expf(2.f*pc));
                float ct = ft*cv + it*tc;
                float ot = 1.f/(1.f + __expf(-(po + Wco[pidx]*ct)));
                float th = 1.f - 2.f/(1.f + __expf(2.f*ct));
                outh[idx] = ot*th;
                outc[idx] = ct;
            }
        }
    }
}

// ---------------------------------------------------------------------------
extern "C" void kernel_launch(void* const* d_in, const int* in_sizes, int n_in,
                              void* d_out, int out_size, void* d_ws, size_t ws_size,
                              hipStream_t stream)
{
    const float* x   = (const float*)d_in[0];
    const float* h   = (const float*)d_in[1];
    const float* c   = (const float*)d_in[2];
    const float* Wx  = (const float*)d_in[3];
    const float* Wh  = (const float*)d_in[4];
    const float* bh  = (const float*)d_in[5];
    const float* Wci = (const float*)d_in[6];
    const float* Wcf = (const float*)d_in[7];
    const float* Wco = (const float*)d_in[8];
    float* out = (float*)d_out;

    unsigned char* xh = (unsigned char*)d_ws;        // 84,934,656 B planes
    __bf16* Wt = (__bf16*)(xh + (size_t)XH_BYTES + 4096); // +slack for over-read

    hipLaunchKernelGGL(xh_transform, dim3(4096), dim3(256), 0, stream, x, h, xh);
    hipLaunchKernelGGL(w_transform,  dim3(2304), dim3(256), 0, stream, Wx, Wh, Wt);
    hipLaunchKernelGGL(convlstm_main, dim3(4096), dim3(256), 0, stream,
                       xh, Wt, bh, c, Wci, Wcf, Wco, out);
}

// Round 5
// 640.219 us; speedup vs baseline: 1.6391x; 1.0170x over previous
//
#include <hip/hip_runtime.h>

// ConvLSTM cell, MI355X. Implicit-GEMM over concat(x,h) channels, bf16 MFMA
// 32x32x16, fused in-register LSTM epilogue.
// R5: R4 + B-fragment dist-1 ping-pong (per-ibk restart), launch_bounds(256,3).

typedef __bf16 bf16x8 __attribute__((ext_vector_type(8)));
typedef float f32x16 __attribute__((ext_vector_type(16)));

#define PLANE_B  20736u                 // 324 positions * 64 B (18x18x32 bf16)
#define XH_BYTES (4096u * PLANE_B)      // 256 b * 16 icblk planes
#define OUT_HALF 16777216u              // B*CH*S

__device__ inline void gload_lds16(const void* g, void* l) {
    __builtin_amdgcn_global_load_lds(
        (const __attribute__((address_space(1))) void*)g,
        (__attribute__((address_space(3))) void*)l, 16, 0, 0);
}

// ---------------------------------------------------------------------------
// P1a: x,h (NCHW fp32) -> padded swizzled bf16 planes.
// addr = (p*64 + ofs) ^ ((p&7)<<4)  (bijective; same formula on read).
__global__ __launch_bounds__(256) void xh_transform(
    const float* __restrict__ x, const float* __restrict__ hh,
    unsigned char* __restrict__ xh)
{
    int blk = blockIdx.x;              // b*16 + ibk
    int b = blk >> 4, ibk = blk & 15;
    const float* src = (ibk < 8) ? (x  + ((size_t)(b*256 + ibk*32)) * 256)
                                 : (hh + ((size_t)(b*256 + (ibk-8)*32)) * 256);
    int t = threadIdx.x;               // t == spatial s
    uint32_t w[16];
#pragma unroll
    for (int i = 0; i < 16; ++i) {
        __bf16 lo = (__bf16)src[(size_t)(2*i  )*256 + t];
        __bf16 hi = (__bf16)src[(size_t)(2*i+1)*256 + t];
        w[i] = (uint32_t)__builtin_bit_cast(unsigned short, lo)
             | ((uint32_t)__builtin_bit_cast(unsigned short, hi) << 16);
    }
    unsigned char* plane = xh + (size_t)blk * PLANE_B;
    int p = ((t >> 4) + 1)*18 + (t & 15) + 1;      // interior position
    uint32_t key  = (uint32_t)(p & 7) << 4;
    uint32_t base = (uint32_t)p * 64u;
#pragma unroll
    for (int k = 0; k < 4; ++k)
        *(uint4*)(plane + ((base + 16u*k) ^ key)) =
            uint4{w[4*k], w[4*k+1], w[4*k+2], w[4*k+3]};
    // zero the 68 border positions (rows 0,17; cols 0,17)
    if (t < 68) {
        int pb;
        if      (t < 18) pb = t;                   // row 0
        else if (t < 36) pb = 17*18 + (t - 18);    // row 17
        else if (t < 52) pb = (t - 35)*18;         // rows 1..16, col 0
        else             pb = (t - 51)*18 + 17;    // rows 1..16, col 17
        uint32_t kb = (uint32_t)(pb & 7) << 4;
        uint32_t bb = (uint32_t)pb * 64u;
        uint4 z{0u,0u,0u,0u};
#pragma unroll
        for (int k = 0; k < 4; ++k)
            *(uint4*)(plane + ((bb + 16u*k) ^ kb)) = z;
    }
}

// ---------------------------------------------------------------------------
// P1b: Wx,Wh (OIHW fp32) -> Wt bf16 in A-fragment order.
__global__ __launch_bounds__(256) void w_transform(
    const float* __restrict__ Wx, const float* __restrict__ Wh,
    __bf16* __restrict__ Wt)
{
    int idx  = blockIdx.x * 256 + threadIdx.x;   // 589824 total
    int lane = idx & 63;
    int chunk = idx >> 6;                        // 9216 chunks
    int half  = chunk & 1;
    int icblk = (chunk >> 1) & 15;
    int fg    = (chunk >> 5) & 3;
    int cb    = (chunk >> 7) & 7;
    int pos   = chunk >> 10;                     // ky*3+kx
    int row = lane & 31, hl = lane >> 5;
    int gate = row & 3, ch8 = row >> 2;
    int oc  = gate*256 + cb*32 + fg*8 + ch8;
    int ic0 = icblk*32 + half*16 + hl*8;
    bf16x8 v;
#pragma unroll
    for (int j = 0; j < 8; ++j) {
        int ic = ic0 + j;
        float w = (ic < 256) ? Wx[((size_t)oc*256 + ic      )*9 + pos]
                             : Wh[((size_t)oc*256 + (ic-256))*9 + pos];
        v[j] = (__bf16)w;
    }
    *(bf16x8*)(Wt + (size_t)chunk*512 + (size_t)lane*8) = v;
}

// ---------------------------------------------------------------------------
// Main. Block = (b, nh, cb): 256m x 64oc'. 4 waves, each 64m x 64oc:
// acc[2][2] f32x16 = 64 AGPR. DMA staging, A dist-1, B dist-1 ping-pong.
__global__ __launch_bounds__(256, 3) void convlstm_main(
    const unsigned char* __restrict__ xh, const __bf16* __restrict__ Wt,
    const float* __restrict__ bh,  const float* __restrict__ cin,
    const float* __restrict__ Wci, const float* __restrict__ Wcf,
    const float* __restrict__ Wco, float* __restrict__ out)
{
    int bid = blockIdx.x;               // b*16 + nh*8 + cb
    int cb  = bid & 7;
    int nh  = (bid >> 3) & 1;
    int b   = bid >> 4;
    int tid = threadIdx.x;
    int lane = tid & 63, wv = tid >> 6;
    int l31 = lane & 31, hl = lane >> 5;

    __shared__ __align__(16) unsigned char lds[2][24576];

    // accumulators init with bias bh[oc]
    f32x16 acc[2][2];
#pragma unroll
    for (int f = 0; f < 2; ++f) {
        int fg = nh*2 + f;
        f32x16 v;
#pragma unroll
        for (int r = 0; r < 16; ++r) {
            int gate = r & 3, q = r >> 2;
            v[r] = bh[gate*256 + cb*32 + fg*8 + 2*q + hl];
        }
        acc[0][f] = v; acc[1][f] = v;
    }

    const unsigned char* planes = xh + (size_t)b * (16u * PLANE_B);

    // stage plane 0 into buffer 0 (linear DMA; plane pre-padded+swizzled)
#pragma unroll
    for (int k = 0; k < 6; ++k)
        gload_lds16(planes + (size_t)(wv*6 + k)*1024u + (size_t)lane*16u,
                    &lds[0][(wv*6 + k)*1024 + lane*16]);

    // per-wave B-frag position bases (m = wv*64 + mf*32 + l31)
    int m0 = wv*64 + l31,       m1 = wv*64 + 32 + l31;
    int pbase0 = (m0 >> 4)*18 + (m0 & 15);
    int pbase1 = (m1 >> 4)*18 + (m1 & 15);
    const uint32_t kbase = (uint32_t)(hl*16);

    const __bf16* wlane = Wt + (size_t)lane * 8;
    auto achunk = [&](int ibk, int ph, int f) -> size_t {
        int pos = ph >> 1, half = ph & 1, fg = nh*2 + f;
        return ((size_t)((pos*8 + cb)*4 + fg))*32 + (size_t)(ibk*2 + half);
    };
    auto bread = [&](const unsigned char* rb, int pbase, int ph) -> bf16x8 {
        int pos = ph >> 1, half = ph & 1;
        int p = pbase + (pos/3)*18 + (pos%3);
        uint32_t byte = ((uint32_t)p*64u + kbase + (uint32_t)(half*32))
                        ^ (((uint32_t)(p & 7)) << 4);
        return *(const bf16x8*)(rb + byte);
    };

    __syncthreads();   // drains stage DMA + joins waves

    // A prologue: phase 0 of icblk 0
    bf16x8 A[2][2];
    A[0][0] = *(const bf16x8*)(wlane + achunk(0, 0, 0)*512);
    A[0][1] = *(const bf16x8*)(wlane + achunk(0, 0, 1)*512);

    for (int ibk = 0; ibk < 16; ++ibk) {
        const int cur = ibk & 1;
        // issue next-plane DMA into the buffer freed last iteration
        if (ibk < 15) {
            const unsigned char* np = planes + (size_t)(ibk+1) * PLANE_B;
#pragma unroll
            for (int k = 0; k < 6; ++k)
                gload_lds16(np + (size_t)(wv*6 + k)*1024u + (size_t)lane*16u,
                            &lds[cur ^ 1][(wv*6 + k)*1024 + lane*16]);
        }
        const unsigned char* rb = lds[cur];

        // B prologue: phase 0 of this ibk (pipeline restarts per ibk —
        // cross-ibk prefetch would race the DMA into the other buffer)
        bf16x8 Bb[2][2];
        Bb[0][0] = bread(rb, pbase0, 0);
        Bb[0][1] = bread(rb, pbase1, 0);

#pragma unroll
        for (int ph = 0; ph < 18; ++ph) {
            // A prefetch distance 1 (wraps into next icblk at ph 17)
            {
                int nib = (ph < 17) ? ibk : ((ibk < 15) ? ibk + 1 : ibk);
                int nph = (ph < 17) ? ph + 1 : 0;
                A[(ph+1)&1][0] = *(const bf16x8*)(wlane + achunk(nib, nph, 0)*512);
                A[(ph+1)&1][1] = *(const bf16x8*)(wlane + achunk(nib, nph, 1)*512);
            }
            // B prefetch distance 1 (not at ph 17 — next data is other buffer)
            if (ph < 17) {
                Bb[(ph+1)&1][0] = bread(rb, pbase0, ph+1);
                Bb[(ph+1)&1][1] = bread(rb, pbase1, ph+1);
            }
            __builtin_amdgcn_s_setprio(1);
            acc[0][0] = __builtin_amdgcn_mfma_f32_32x32x16_bf16(A[ph&1][0], Bb[ph&1][0], acc[0][0], 0, 0, 0);
            acc[0][1] = __builtin_amdgcn_mfma_f32_32x32x16_bf16(A[ph&1][1], Bb[ph&1][0], acc[0][1], 0, 0, 0);
            acc[1][0] = __builtin_amdgcn_mfma_f32_32x32x16_bf16(A[ph&1][0], Bb[ph&1][1], acc[1][0], 0, 0, 0);
            acc[1][1] = __builtin_amdgcn_mfma_f32_32x32x16_bf16(A[ph&1][1], Bb[ph&1][1], acc[1][1], 0, 0, 0);
            __builtin_amdgcn_s_setprio(0);
        }
        __syncthreads();   // DMA for next buffer complete; separates buffers
    }

    // fused LSTM epilogue. col = l31 (m), r = 4*q + gate,
    // ch = cb*32 + fg*8 + 2*q + hl.
    float* outh = out;
    float* outc = out + (size_t)OUT_HALF;
    const size_t bOff = (size_t)b * (256*256);
#pragma unroll
    for (int mf = 0; mf < 2; ++mf) {
        int m = wv*64 + mf*32 + l31;
#pragma unroll
        for (int f = 0; f < 2; ++f) {
            int fg = nh*2 + f;
#pragma unroll
            for (int q = 0; q < 4; ++q) {
                int ch = cb*32 + fg*8 + 2*q + hl;
                size_t pidx = (size_t)ch*256 + (size_t)m;
                size_t idx  = bOff + pidx;
                float cv = cin[idx];
                float pi = acc[mf][f][4*q+0];
                float pf = acc[mf][f][4*q+1];
                float pc = acc[mf][f][4*q+2];
                float po = acc[mf][f][4*q+3];
                float it = 1.f/(1.f + __expf(-(pi + Wci[pidx]*cv)));
                float ft = 1.f/(1.f + __expf(-(pf + Wcf[pidx]*cv)));
                float tc = 1.f - 2.f/(1.f + __expf(2.f*pc));
                float ct = ft*cv + it*tc;
                float ot = 1.f/(1.f + __expf(-(po + Wco[pidx]*ct)));
                float th = 1.f - 2.f/(1.f + __expf(2.f*ct));
                outh[idx] = ot*th;
                outc[idx] = ct;
            }
        }
    }
}

// ---------------------------------------------------------------------------
extern "C" void kernel_launch(void* const* d_in, const int* in_sizes, int n_in,
                              void* d_out, int out_size, void* d_ws, size_t ws_size,
                              hipStream_t stream)
{
    const float* x   = (const float*)d_in[0];
    const float* h   = (const float*)d_in[1];
    const float* c   = (const float*)d_in[2];
    const float* Wx  = (const float*)d_in[3];
    const float* Wh  = (const float*)d_in[4];
    const float* bh  = (const float*)d_in[5];
    const float* Wci = (const float*)d_in[6];
    const float* Wcf = (const float*)d_in[7];
    const float* Wco = (const float*)d_in[8];
    float* out = (float*)d_out;

    unsigned char* xh = (unsigned char*)d_ws;        // padded plane store
    __bf16* Wt = (__bf16*)(xh + (size_t)XH_BYTES + 4096); // +slack

    hipLaunchKernelGGL(xh_transform, dim3(4096), dim3(256), 0, stream, x, h, xh);
    hipLaunchKernelGGL(w_transform,  dim3(2304), dim3(256), 0, stream, Wx, Wh, Wt);
    hipLaunchKernelGGL(convlstm_main, dim3(4096), dim3(256), 0, stream,
                       xh, Wt, bh, c, Wci, Wcf, Wco, out);
}